// Round 1
// baseline (301.403 us; speedup 1.0000x reference)
//
#include <hip/hip_runtime.h>
#include <math.h>

#define GH 224
#define GW 224
#define GN (GH*GW)          // 50176
#define KNN 121             // 11x11
#define NT 25
#define NBLK 196            // GN / 256

// ws layout (floats):
// [0..12)            bounds[c*4+b] = 0.05*sum(w)
// [16..40)           tmm: (tmin,tmax) per image idx
// [64..664)          lam[3][4][50]
// [1024, 1024+12N)   F   (dtm values per image)
// [1024+12N, +24N)   TD  (is_min ? death : -inf)
#define WS_F 1024
#define WS_TD (1024 + 12*(size_t)GN)

__global__ __launch_bounds__(256) void k_sums(const float* __restrict__ in, float* __restrict__ ws) {
    int idx = blockIdx.x;            // c*4+b
    int c = idx >> 2, b = idx & 3;
    const float* w = in + (size_t)(b*3 + c) * GN;
    float s = 0.f;
    for (int p = threadIdx.x; p < GN; p += 256) s += w[p];
    __shared__ float sh[256];
    sh[threadIdx.x] = s; __syncthreads();
    for (int st = 128; st > 0; st >>= 1) {
        if (threadIdx.x < st) sh[threadIdx.x] += sh[threadIdx.x + st];
        __syncthreads();
    }
    if (threadIdx.x == 0) ws[idx] = 0.05f * sh[0];
}

__global__ __launch_bounds__(256) void k_dtm(const float* __restrict__ in, float* __restrict__ ws) {
    // build stable-sorted offset table (matches np.argsort(d2, kind="stable"))
    __shared__ int sdy[KNN], sdx[KNN];
    __shared__ float sd2[KNN];
    int t = threadIdx.x;
    if (t < KNN) {
        int dy = t / 11 - 5, dx = t % 11 - 5;
        int d2 = dy*dy + dx*dx;
        int rank = 0;
        for (int j = 0; j < KNN; j++) {
            int ey = j / 11 - 5, ex = j % 11 - 5;
            int e2 = ey*ey + ex*ex;
            rank += (e2 < d2) || (e2 == d2 && j < t);
        }
        sdy[rank] = dy; sdx[rank] = dx; sd2[rank] = (float)d2;
    }
    __syncthreads();

    int idx = blockIdx.x / NBLK;     // c*4+b
    int p   = (blockIdx.x % NBLK) * 256 + threadIdx.x;
    int c = idx >> 2, b = idx & 3;
    const float* w = in + (size_t)(b*3 + c) * GN;
    float bound = ws[idx];
    int y = p / GW, x = p % GW;
    float cum = 0.f, acc = 0.f;
    for (int j = 0; j < KNN; j++) {
        int ny = y + sdy[j]; ny = ny < 0 ? 0 : (ny > GH-1 ? GH-1 : ny);
        int nx = x + sdx[j]; nx = nx < 0 ? 0 : (nx > GW-1 ? GW-1 : nx);
        float nw = w[ny*GW + nx];
        cum += nw;
        float v = bound - (cum - nw);           // remaining mass incl. this nbr
        v = v < 0.f ? 0.f : v;
        v = v > nw ? nw : v;                    // clip(bound-(cum-nw), 0, nw)
        acc += v * sd2[j];
    }
    float f = sqrtf(acc / bound + 1e-12f);
    ws[WS_F + (size_t)idx * GN + p] = f;
}

__global__ __launch_bounds__(256) void k_win(float* __restrict__ ws) {
    int idx = blockIdx.x / NBLK;
    int p   = (blockIdx.x % NBLK) * 256 + threadIdx.x;
    const float* F = ws + WS_F + (size_t)idx * GN;
    int y = p / GW, x = p % GW;
    float f = F[p];
    float mn = f, mx = f;
    int y0 = y > 0 ? y-1 : 0, y1 = y < GH-1 ? y+1 : GH-1;
    int x0 = x > 0 ? x-1 : 0, x1 = x < GW-1 ? x+1 : GW-1;
    for (int yy = y0; yy <= y1; yy++)
        for (int xx = x0; xx <= x1; xx++) {
            float v = F[yy*GW + xx];
            mn = fminf(mn, v); mx = fmaxf(mx, v);
        }
    // is_min = (f <= window min incl. center). Non-minima -> -inf so tent<=0.
    float td = (f <= mn) ? mx : -INFINITY;
    ws[WS_TD + (size_t)idx * GN + p] = td;
}

__global__ __launch_bounds__(256) void k_minmax(float* __restrict__ ws) {
    int idx = blockIdx.x;
    const float* F = ws + WS_F + (size_t)idx * GN;
    float mn = INFINITY, mx = -INFINITY;
    for (int p = threadIdx.x; p < GN; p += 256) {
        float v = F[p];
        mn = fminf(mn, v); mx = fmaxf(mx, v);
    }
    __shared__ float smn[256], smx[256];
    smn[threadIdx.x] = mn; smx[threadIdx.x] = mx; __syncthreads();
    for (int st = 128; st > 0; st >>= 1) {
        if (threadIdx.x < st) {
            smn[threadIdx.x] = fminf(smn[threadIdx.x], smn[threadIdx.x + st]);
            smx[threadIdx.x] = fmaxf(smx[threadIdx.x], smx[threadIdx.x + st]);
        }
        __syncthreads();
    }
    if (threadIdx.x == 0) { ws[16 + 2*idx] = smn[0]; ws[16 + 2*idx + 1] = smx[0]; }
}

__global__ __launch_bounds__(256) void k_top2(float* __restrict__ ws) {
    int bi = blockIdx.x;                 // c*100 + b*25 + t
    int c = bi / 100, rem = bi % 100, b = rem / 25, t = rem % 25;
    int idx = c*4 + b;
    float tmin = ws[16 + 2*idx], tmax = ws[16 + 2*idx + 1];
    float ts = tmin + (tmax - tmin) * ((float)t / 24.0f);
    const float* F  = ws + WS_F  + (size_t)idx * GN;
    const float* TD = ws + WS_TD + (size_t)idx * GN;
    float m0 = 0.f, m1 = 0.f;            // all tents >= 0; N >> 2 so 0-init exact
    for (int p = threadIdx.x; p < GN; p += 256) {
        float birth = F[p], td = TD[p];
        float v = fmaxf(fminf(ts - birth, td - ts), 0.f);
        float n0 = fmaxf(m0, v);
        m1 = fmaxf(m1, fminf(m0, v));
        m0 = n0;
    }
    __shared__ float s0[256], s1[256];
    s0[threadIdx.x] = m0; s1[threadIdx.x] = m1; __syncthreads();
    for (int st = 128; st > 0; st >>= 1) {
        if (threadIdx.x < st) {
            float a0 = s0[threadIdx.x], a1 = s1[threadIdx.x];
            float b0 = s0[threadIdx.x + st], b1 = s1[threadIdx.x + st];
            s0[threadIdx.x] = fmaxf(a0, b0);
            s1[threadIdx.x] = fmaxf(fminf(a0, b0), fmaxf(a1, b1));  // exact 2nd-of-union
        }
        __syncthreads();
    }
    if (threadIdx.x == 0) {
        ws[64 + (size_t)idx * 50 + t*2    ] = s0[0];
        ws[64 + (size_t)idx * 50 + t*2 + 1] = s1[0];
    }
}

__global__ __launch_bounds__(640) void k_head(const float* __restrict__ W1, const float* __restrict__ b1,
                                              const float* __restrict__ W2, const float* __restrict__ b2,
                                              const float* __restrict__ W3, const float* __restrict__ b3,
                                              const float* __restrict__ fcw, const float* __restrict__ fcb,
                                              const float* __restrict__ ws, float* __restrict__ out) {
    __shared__ float x[600];             // [b][150]
    int tid = threadIdx.x;
    if (tid < 600) {
        int b = tid / 150, j = tid % 150, c = j / 50, o = j % 50;
        const float* Wc = (c == 0) ? W1 : (c == 1) ? W2 : W3;
        const float* bc = (c == 0) ? b1 : (c == 1) ? b2 : b3;
        const float* lam = ws + 64 + (size_t)(c*4 + b) * 50;
        float acc = bc[o];
        for (int f = 0; f < 50; f++) acc += lam[f] * Wc[o*50 + f];
        x[tid] = acc;
    }
    __syncthreads();
    if (tid < 150) {                     // signal = sum_b |x|
        float s = 0.f;
        for (int b = 0; b < 4; b++) s += fabsf(x[b*150 + tid]);
        out[28 + tid] = s;
    }
    if (tid >= 256 && tid < 284) {       // output = relu(x) @ fc_w.T + fc_b
        int t2 = tid - 256, b = t2 / 7, o = t2 % 7;
        float acc = fcb[o];
        for (int j = 0; j < 150; j++) acc += fmaxf(x[b*150 + j], 0.f) * fcw[o*150 + j];
        out[b*7 + o] = acc;
    }
}

extern "C" void kernel_launch(void* const* d_in, const int* in_sizes, int n_in,
                              void* d_out, int out_size, void* d_ws, size_t ws_size,
                              hipStream_t stream) {
    const float* in  = (const float*)d_in[0];
    const float* W1  = (const float*)d_in[1];
    const float* b1  = (const float*)d_in[2];
    const float* W2  = (const float*)d_in[3];
    const float* b2  = (const float*)d_in[4];
    const float* W3  = (const float*)d_in[5];
    const float* b3  = (const float*)d_in[6];
    const float* fcw = (const float*)d_in[7];
    const float* fcb = (const float*)d_in[8];
    float* ws  = (float*)d_ws;
    float* out = (float*)d_out;

    k_sums  <<<12,        256, 0, stream>>>(in, ws);
    k_dtm   <<<12 * NBLK, 256, 0, stream>>>(in, ws);
    k_win   <<<12 * NBLK, 256, 0, stream>>>(ws);
    k_minmax<<<12,        256, 0, stream>>>(ws);
    k_top2  <<<300,       256, 0, stream>>>(ws);
    k_head  <<<1,         640, 0, stream>>>(W1, b1, W2, b2, W3, b3, fcw, fcb, ws, out);
}

// Round 2
// 184.274 us; speedup vs baseline: 1.6356x; 1.6356x over previous
//
#include <hip/hip_runtime.h>
#include <math.h>

#define GH 224
#define GW 224
#define GN (GH*GW)          // 50176
#define KNN 121             // 11x11
#define NT 25
#define NBLK 196            // GN / 256  (k_dtm pixel blocks)
#define NCH 49              // pixel chunks for sums/top2 (1024 px each)

// ws layout (floats):
// [0..12)      bounds partial sums (atomicAdd; bound = 0.05*ws[idx])
// [16..40)     per-idx (mn_invbits, mx_bits) via uint atomicMax
// [64..29464)  top2 partials [idx][chunk][t][2]  (12*49*25*2)
// [32768, +12*GN) F (dtm values per image)
#define WS_TOP 64
#define WS_F   32768

__global__ __launch_bounds__(256) void k_sums(const float* __restrict__ in, float* __restrict__ ws) {
    int idx = blockIdx.x / NCH, chunk = blockIdx.x % NCH;
    int c = idx >> 2, b = idx & 3;
    const float4* w = (const float4*)(in + (size_t)(b*3 + c) * GN);
    float4 v = w[chunk*256 + threadIdx.x];
    float s = v.x + v.y + v.z + v.w;
    #pragma unroll
    for (int off = 32; off > 0; off >>= 1) s += __shfl_down(s, off);
    __shared__ float sh[4];
    if ((threadIdx.x & 63) == 0) sh[threadIdx.x >> 6] = s;
    __syncthreads();
    if (threadIdx.x == 0) atomicAdd(&ws[idx], sh[0] + sh[1] + sh[2] + sh[3]);
}

__global__ __launch_bounds__(256) void k_dtm(const float* __restrict__ in, float* __restrict__ ws) {
    // stable-sorted offset table (matches np.argsort(d2, kind="stable"))
    __shared__ int sdy[KNN], sdx[KNN];
    __shared__ float sd2[KNN];
    int t = threadIdx.x;
    if (t < KNN) {
        int dy = t / 11 - 5, dx = t % 11 - 5;
        int d2 = dy*dy + dx*dx;
        int rank = 0;
        for (int j = 0; j < KNN; j++) {
            int ey = j / 11 - 5, ex = j % 11 - 5;
            int e2 = ey*ey + ex*ex;
            rank += (e2 < d2) || (e2 == d2 && j < t);
        }
        sdy[rank] = dy; sdx[rank] = dx; sd2[rank] = (float)d2;
    }
    __syncthreads();

    int idx = blockIdx.x / NBLK;
    int p   = (blockIdx.x % NBLK) * 256 + threadIdx.x;
    int c = idx >> 2, b = idx & 3;
    const float* w = in + (size_t)(b*3 + c) * GN;
    float bound = 0.05f * ws[idx];
    int y = p / GW, x = p % GW;
    float cum = 0.f, acc = 0.f;
    for (int j = 0; j < KNN; j++) {
        int ny = y + sdy[j]; ny = ny < 0 ? 0 : (ny > GH-1 ? GH-1 : ny);
        int nx = x + sdx[j]; nx = nx < 0 ? 0 : (nx > GW-1 ? GW-1 : nx);
        float nw = w[ny*GW + nx];
        cum += nw;
        float v = bound - (cum - nw);
        v = v < 0.f ? 0.f : v;
        v = v > nw ? nw : v;
        acc += v * sd2[j];
    }
    float f = sqrtf(acc / bound + 1e-12f);
    ws[WS_F + (size_t)idx * GN + p] = f;

    // fused global min/max of F (deterministic ordered-uint atomics; f > 0)
    float mnv = f, mxv = f;
    #pragma unroll
    for (int off = 32; off > 0; off >>= 1) {
        mnv = fminf(mnv, __shfl_down(mnv, off));
        mxv = fmaxf(mxv, __shfl_down(mxv, off));
    }
    __shared__ float smn[4], smx[4];
    if ((threadIdx.x & 63) == 0) { smn[threadIdx.x>>6] = mnv; smx[threadIdx.x>>6] = mxv; }
    __syncthreads();
    if (threadIdx.x == 0) {
        float bm = fminf(fminf(smn[0], smn[1]), fminf(smn[2], smn[3]));
        float bx = fmaxf(fmaxf(smx[0], smx[1]), fmaxf(smx[2], smx[3]));
        atomicMax((unsigned int*)&ws[16 + 2*idx], ~__float_as_uint(bm));
        atomicMax((unsigned int*)&ws[17 + 2*idx],  __float_as_uint(bx));
    }
}

__global__ __launch_bounds__(256) void k_top2p(float* __restrict__ ws) {
    int idx = blockIdx.x / NCH, chunk = blockIdx.x % NCH;
    const float* F = ws + WS_F + (size_t)idx * GN;
    float tmin = __uint_as_float(~((const unsigned int*)ws)[16 + 2*idx]);
    float tmax = __uint_as_float( ((const unsigned int*)ws)[17 + 2*idx]);
    float dr = tmax - tmin;
    float ts[NT], m0[NT], m1[NT];
    #pragma unroll
    for (int t = 0; t < NT; t++) {
        ts[t] = tmin + dr * ((float)t / 24.0f);
        m0[t] = 0.f; m1[t] = 0.f;
    }
    for (int k = 0; k < 4; k++) {
        int p = chunk*1024 + k*256 + threadIdx.x;
        int y = p / GW, x = p % GW;
        float f = F[p];
        float mn = f, mx = f;
        int y0 = y > 0 ? y-1 : 0, y1 = y < GH-1 ? y+1 : GH-1;
        int x0 = x > 0 ? x-1 : 0, x1 = x < GW-1 ? x+1 : GW-1;
        for (int yy = y0; yy <= y1; yy++)
            for (int xx = x0; xx <= x1; xx++) {
                float v = F[yy*GW + xx];
                mn = fminf(mn, v); mx = fmaxf(mx, v);
            }
        float td = (f <= mn) ? mx : -INFINITY;   // non-minima -> tent 0
        #pragma unroll
        for (int t = 0; t < NT; t++) {
            float v = fmaxf(fminf(ts[t] - f, td - ts[t]), 0.f);
            float n0 = fmaxf(m0[t], v);
            m1[t] = fmaxf(m1[t], fminf(m0[t], v));
            m0[t] = n0;
        }
    }
    // wave-level exact top-2 merge
    #pragma unroll
    for (int t = 0; t < NT; t++) {
        #pragma unroll
        for (int off = 32; off > 0; off >>= 1) {
            float b0 = __shfl_down(m0[t], off);
            float b1 = __shfl_down(m1[t], off);
            float n0 = fmaxf(m0[t], b0);
            m1[t] = fmaxf(fminf(m0[t], b0), fmaxf(m1[t], b1));
            m0[t] = n0;
        }
    }
    __shared__ float red[4][2*NT];
    if ((threadIdx.x & 63) == 0) {
        int w = threadIdx.x >> 6;
        #pragma unroll
        for (int t = 0; t < NT; t++) { red[w][2*t] = m0[t]; red[w][2*t+1] = m1[t]; }
    }
    __syncthreads();
    if (threadIdx.x < NT) {
        int t = threadIdx.x;
        float a0 = red[0][2*t], a1 = red[0][2*t+1];
        #pragma unroll
        for (int w = 1; w < 4; w++) {
            float b0 = red[w][2*t], b1 = red[w][2*t+1];
            float n0 = fmaxf(a0, b0);
            a1 = fmaxf(fminf(a0, b0), fmaxf(a1, b1));
            a0 = n0;
        }
        size_t o = WS_TOP + (size_t)((idx*NCH + chunk)*NT + t) * 2;
        ws[o] = a0; ws[o+1] = a1;
    }
}

__global__ __launch_bounds__(640) void k_head(const float* __restrict__ W1, const float* __restrict__ b1,
                                              const float* __restrict__ W2, const float* __restrict__ b2,
                                              const float* __restrict__ W3, const float* __restrict__ b3,
                                              const float* __restrict__ fcw, const float* __restrict__ fcb,
                                              const float* __restrict__ ws, float* __restrict__ out) {
    __shared__ float lamS[12*50];
    __shared__ float x[600];
    int tid = threadIdx.x;
    if (tid < 300) {                     // merge 49 partial top2s per (idx,t)
        int idx = tid / NT, t = tid % NT;
        const float* base = ws + WS_TOP + (size_t)(idx*NCH*NT + t) * 2;
        float a0 = 0.f, a1 = 0.f;
        for (int ch = 0; ch < NCH; ch++) {
            float b0 = base[ch*NT*2], b1 = base[ch*NT*2 + 1];
            float n0 = fmaxf(a0, b0);
            a1 = fmaxf(fminf(a0, b0), fmaxf(a1, b1));
            a0 = n0;
        }
        lamS[idx*50 + t*2] = a0; lamS[idx*50 + t*2 + 1] = a1;
    }
    __syncthreads();
    if (tid < 600) {
        int b = tid / 150, j = tid % 150, c = j / 50, o = j % 50;
        const float* Wc = (c == 0) ? W1 : (c == 1) ? W2 : W3;
        const float* bc = (c == 0) ? b1 : (c == 1) ? b2 : b3;
        const float* lam = lamS + (c*4 + b) * 50;
        float acc = bc[o];
        for (int f = 0; f < 50; f++) acc += lam[f] * Wc[o*50 + f];
        x[tid] = acc;
    }
    __syncthreads();
    if (tid < 150) {                     // signal = sum_b |x|
        float s = 0.f;
        for (int b = 0; b < 4; b++) s += fabsf(x[b*150 + tid]);
        out[28 + tid] = s;
    }
    if (tid >= 256 && tid < 284) {       // output = relu(x) @ fc_w.T + fc_b
        int t2 = tid - 256, b = t2 / 7, o = t2 % 7;
        float acc = fcb[o];
        for (int j = 0; j < 150; j++) acc += fmaxf(x[b*150 + j], 0.f) * fcw[o*150 + j];
        out[b*7 + o] = acc;
    }
}

extern "C" void kernel_launch(void* const* d_in, const int* in_sizes, int n_in,
                              void* d_out, int out_size, void* d_ws, size_t ws_size,
                              hipStream_t stream) {
    const float* in  = (const float*)d_in[0];
    const float* W1  = (const float*)d_in[1];
    const float* b1  = (const float*)d_in[2];
    const float* W2  = (const float*)d_in[3];
    const float* b2  = (const float*)d_in[4];
    const float* W3  = (const float*)d_in[5];
    const float* b3  = (const float*)d_in[6];
    const float* fcw = (const float*)d_in[7];
    const float* fcb = (const float*)d_in[8];
    float* ws  = (float*)d_ws;
    float* out = (float*)d_out;

    hipMemsetAsync(ws, 0, 40 * sizeof(float), stream);   // bounds + minmax slots
    k_sums <<<12 * NCH,  256, 0, stream>>>(in, ws);
    k_dtm  <<<12 * NBLK, 256, 0, stream>>>(in, ws);
    k_top2p<<<12 * NCH,  256, 0, stream>>>(ws);
    k_head <<<1,         640, 0, stream>>>(W1, b1, W2, b2, W3, b3, fcw, fcb, ws, out);
}

// Round 3
// 148.748 us; speedup vs baseline: 2.0263x; 1.2388x over previous
//
#include <hip/hip_runtime.h>
#include <math.h>

#define GH 224
#define GW 224
#define GN (GH*GW)          // 50176
#define NT 25
#define NCH 49              // 1024-px chunks for sums/top2
#define LW 42               // dtm tile width  (32 + 2*5)
#define LH 18               // dtm tile height (8 + 2*5)

// ws layout (floats):
// [0..12)      bounds partial sums (atomicAdd; bound = 0.05*ws[idx])
// [16..40)     per-idx (mn_invbits, mx_bits) via uint atomicMax
// [64..29464)  top2 partials [idx][chunk][t][2]
// [32768, +12*GN) F (dtm values per image)
#define WS_TOP 64
#define WS_F   32768

// compile-time stable-sorted neighbor table (matches np.argsort(d2, kind="stable"))
struct NbrTbl { int off[121]; float d2[121]; };
constexpr NbrTbl make_tbl() {
    NbrTbl t{};
    for (int i = 0; i < 121; i++) {
        int dy = i / 11 - 5, dx = i % 11 - 5;
        int d2 = dy*dy + dx*dx;
        int rank = 0;
        for (int j = 0; j < 121; j++) {
            int ey = j / 11 - 5, ex = j % 11 - 5;
            int e2 = ey*ey + ex*ex;
            rank += (e2 < d2) || (e2 == d2 && j < i);
        }
        t.off[rank] = (dy + 5) * LW + (dx + 5);
        t.d2[rank]  = (float)d2;
    }
    return t;
}
constexpr NbrTbl TBL = make_tbl();

__global__ __launch_bounds__(256) void k_sums(const float* __restrict__ in, float* __restrict__ ws) {
    int idx = blockIdx.x / NCH, chunk = blockIdx.x % NCH;
    int c = idx >> 2, b = idx & 3;
    const float4* w = (const float4*)(in + (size_t)(b*3 + c) * GN);
    float4 v = w[chunk*256 + threadIdx.x];
    float s = v.x + v.y + v.z + v.w;
    #pragma unroll
    for (int off = 32; off > 0; off >>= 1) s += __shfl_down(s, off);
    __shared__ float sh[4];
    if ((threadIdx.x & 63) == 0) sh[threadIdx.x >> 6] = s;
    __syncthreads();
    if (threadIdx.x == 0) atomicAdd(&ws[idx], sh[0] + sh[1] + sh[2] + sh[3]);
}

__global__ __launch_bounds__(256) void k_dtm(const float* __restrict__ in, float* __restrict__ ws) {
    int idx  = blockIdx.x / 196;          // c*4+b
    int tblk = blockIdx.x % 196;
    int by = tblk / 7, bx = tblk % 7;     // tile origin (by*8, bx*32)
    int c = idx >> 2, b = idx & 3;
    const float* w = in + (size_t)(b*3 + c) * GN;

    __shared__ float tile[LH * LW];       // border-clamped halo tile
    for (int i = threadIdx.x; i < LH * LW; i += 256) {
        int hr = i / LW, hc = i % LW;
        int gy = by*8  + hr - 5; gy = gy < 0 ? 0 : (gy > GH-1 ? GH-1 : gy);
        int gx = bx*32 + hc - 5; gx = gx < 0 ? 0 : (gx > GW-1 ? GW-1 : gx);
        tile[i] = w[gy*GW + gx];
    }
    __syncthreads();

    float bound = 0.05f * ws[idx];
    int ty = threadIdx.x >> 5, tx = threadIdx.x & 31;
    const float* base = tile + ty*LW + tx;   // halo corner of this pixel
    float cum = 0.f, acc = 0.f;
    #pragma unroll
    for (int j = 0; j < 121; j++) {          // ds_read_b32 with immediate offset
        float nw = base[TBL.off[j]];
        float v = bound - cum;               // bound - (cum excl. this nbr)
        cum += nw;
        v = v < 0.f ? 0.f : v;
        v = v > nw ? nw : v;
        acc = fmaf(v, TBL.d2[j], acc);
    }
    float f = sqrtf(acc / bound + 1e-12f);
    int p = (by*8 + ty)*GW + bx*32 + tx;
    ws[WS_F + (size_t)idx * GN + p] = f;

    // fused global min/max of F (deterministic ordered-uint atomics; f > 0)
    float mnv = f, mxv = f;
    #pragma unroll
    for (int off = 32; off > 0; off >>= 1) {
        mnv = fminf(mnv, __shfl_down(mnv, off));
        mxv = fmaxf(mxv, __shfl_down(mxv, off));
    }
    __shared__ float smn[4], smx[4];
    if ((threadIdx.x & 63) == 0) { smn[threadIdx.x>>6] = mnv; smx[threadIdx.x>>6] = mxv; }
    __syncthreads();
    if (threadIdx.x == 0) {
        float bm = fminf(fminf(smn[0], smn[1]), fminf(smn[2], smn[3]));
        float bx2 = fmaxf(fmaxf(smx[0], smx[1]), fmaxf(smx[2], smx[3]));
        atomicMax((unsigned int*)&ws[16 + 2*idx], ~__float_as_uint(bm));
        atomicMax((unsigned int*)&ws[17 + 2*idx],  __float_as_uint(bx2));
    }
}

__global__ __launch_bounds__(256) void k_top2p(float* __restrict__ ws) {
    int idx = blockIdx.x / NCH, chunk = blockIdx.x % NCH;
    const float* F = ws + WS_F + (size_t)idx * GN;
    __shared__ float bb[1024], dd[1024];
    __shared__ int cnt;
    __shared__ float q0[NT][10], q1[NT][10];
    int tid = threadIdx.x;
    if (tid == 0) cnt = 0;
    __syncthreads();

    // Phase A: detect 3x3 local minima, compact (birth, death) into LDS
    for (int k = 0; k < 4; k++) {
        int p = chunk*1024 + k*256 + tid;
        int y = p / GW, x = p % GW;
        float f = F[p];
        float mn = f, mx = f;
        int y0 = y > 0 ? y-1 : 0, y1 = y < GH-1 ? y+1 : GH-1;
        int x0 = x > 0 ? x-1 : 0, x1 = x < GW-1 ? x+1 : GW-1;
        for (int yy = y0; yy <= y1; yy++)
            for (int xx = x0; xx <= x1; xx++) {
                float v = F[yy*GW + xx];
                mn = fminf(mn, v); mx = fmaxf(mx, v);
            }
        if (f <= mn) {                       // is_min
            int slot = atomicAdd(&cnt, 1);
            bb[slot] = f; dd[slot] = mx;
        }
    }
    __syncthreads();
    int nm = cnt;

    // Phase B: (t, sub-chunk) distributed top-2 over the minima list
    float tmin = __uint_as_float(~((const unsigned int*)ws)[16 + 2*idx]);
    float tmax = __uint_as_float( ((const unsigned int*)ws)[17 + 2*idx]);
    float dr = tmax - tmin;
    if (tid < 250) {
        int t = tid / 10, sub = tid % 10;
        float ts = tmin + dr * ((float)t / 24.0f);
        float a0 = 0.f, a1 = 0.f;
        for (int i = sub; i < nm; i += 10) {
            float v = fmaxf(fminf(ts - bb[i], dd[i] - ts), 0.f);
            float n0 = fmaxf(a0, v);
            a1 = fmaxf(a1, fminf(a0, v));
            a0 = n0;
        }
        q0[t][sub] = a0; q1[t][sub] = a1;
    }
    __syncthreads();
    if (tid < NT) {
        float a0 = q0[tid][0], a1 = q1[tid][0];
        #pragma unroll
        for (int s = 1; s < 10; s++) {
            float b0 = q0[tid][s], b1 = q1[tid][s];
            float n0 = fmaxf(a0, b0);
            a1 = fmaxf(fminf(a0, b0), fmaxf(a1, b1));
            a0 = n0;
        }
        size_t o = WS_TOP + (size_t)((idx*NCH + chunk)*NT + tid) * 2;
        ws[o] = a0; ws[o+1] = a1;
    }
}

__global__ __launch_bounds__(640) void k_head(const float* __restrict__ W1, const float* __restrict__ b1,
                                              const float* __restrict__ W2, const float* __restrict__ b2,
                                              const float* __restrict__ W3, const float* __restrict__ b3,
                                              const float* __restrict__ fcw, const float* __restrict__ fcb,
                                              const float* __restrict__ ws, float* __restrict__ out) {
    __shared__ float lamS[12*50];
    __shared__ float x[600];
    int tid = threadIdx.x;
    if (tid < 300) {                     // merge 49 partial top2s per (idx,t)
        int idx = tid / NT, t = tid % NT;
        const float* base = ws + WS_TOP + (size_t)(idx*NCH*NT + t) * 2;
        float a0 = 0.f, a1 = 0.f;
        for (int ch = 0; ch < NCH; ch++) {
            float b0 = base[ch*NT*2], b1 = base[ch*NT*2 + 1];
            float n0 = fmaxf(a0, b0);
            a1 = fmaxf(fminf(a0, b0), fmaxf(a1, b1));
            a0 = n0;
        }
        lamS[idx*50 + t*2] = a0; lamS[idx*50 + t*2 + 1] = a1;
    }
    __syncthreads();
    if (tid < 600) {
        int b = tid / 150, j = tid % 150, c = j / 50, o = j % 50;
        const float* Wc = (c == 0) ? W1 : (c == 1) ? W2 : W3;
        const float* bc = (c == 0) ? b1 : (c == 1) ? b2 : b3;
        const float* lam = lamS + (c*4 + b) * 50;
        float acc = bc[o];
        for (int f = 0; f < 50; f++) acc += lam[f] * Wc[o*50 + f];
        x[tid] = acc;
    }
    __syncthreads();
    if (tid < 150) {                     // signal = sum_b |x|
        float s = 0.f;
        for (int b = 0; b < 4; b++) s += fabsf(x[b*150 + tid]);
        out[28 + tid] = s;
    }
    if (tid >= 256 && tid < 284) {       // output = relu(x) @ fc_w.T + fc_b
        int t2 = tid - 256, b = t2 / 7, o = t2 % 7;
        float acc = fcb[o];
        for (int j = 0; j < 150; j++) acc += fmaxf(x[b*150 + j], 0.f) * fcw[o*150 + j];
        out[b*7 + o] = acc;
    }
}

extern "C" void kernel_launch(void* const* d_in, const int* in_sizes, int n_in,
                              void* d_out, int out_size, void* d_ws, size_t ws_size,
                              hipStream_t stream) {
    const float* in  = (const float*)d_in[0];
    const float* W1  = (const float*)d_in[1];
    const float* b1  = (const float*)d_in[2];
    const float* W2  = (const float*)d_in[3];
    const float* b2  = (const float*)d_in[4];
    const float* W3  = (const float*)d_in[5];
    const float* b3  = (const float*)d_in[6];
    const float* fcw = (const float*)d_in[7];
    const float* fcb = (const float*)d_in[8];
    float* ws  = (float*)d_ws;
    float* out = (float*)d_out;

    hipMemsetAsync(ws, 0, 40 * sizeof(float), stream);   // bounds + minmax slots
    k_sums <<<12 * NCH, 256, 0, stream>>>(in, ws);
    k_dtm  <<<12 * 196, 256, 0, stream>>>(in, ws);
    k_top2p<<<12 * NCH, 256, 0, stream>>>(ws);
    k_head <<<1,        640, 0, stream>>>(W1, b1, W2, b2, W3, b3, fcw, fcb, ws, out);
}